// Round 5
// baseline (93.006 us; speedup 1.0000x reference)
//
#include <hip/hip_runtime.h>
#include <stdint.h>

using bf16x8 = __attribute__((ext_vector_type(8))) __bf16;
using f32x4v = __attribute__((ext_vector_type(4))) float;

__device__ __forceinline__ unsigned int f2bf(float f) {
  unsigned int u = __float_as_uint(f);
  return (u + 0x7FFFu + ((u >> 16) & 1u)) >> 16;  // RNE f32->bf16
}

// =====================================================================
// k0b: codebook f32 [1024][256] -> bf16 in MFMA FRAGMENT order + 0.5||e||^2
// (unchanged from R4 — verified)
// =====================================================================
__global__ __launch_bounds__(64) void k0b_cb(const float* __restrict__ cb,
                                             char* __restrict__ cbb,
                                             float* __restrict__ hn) {
  const int code = blockIdx.x, l = threadIdx.x;
  const float4 v = *(const float4*)(cb + code * 256 + l * 4);
  float ss = v.x * v.x + v.y * v.y + v.z * v.z + v.w * v.w;
  uint2 p;
  p.x = f2bf(v.x) | (f2bf(v.y) << 16);
  p.y = f2bf(v.z) | (f2bf(v.w) << 16);
  const int addr = (((code >> 4) * 8 + (l >> 3)) << 10) +
                   ((((l & 7) >> 1) * 16 + (code & 15)) << 4) + (l & 1) * 8;
  *(uint2*)(cbb + addr) = p;
#pragma unroll
  for (int s = 32; s; s >>= 1) ss += __shfl_down(ss, s, 64);
  if (l == 0) hn[code] = 0.5f * ss;
}

// =====================================================================
// k1_fused: 512 blocks x 256 thr (4 waves), block = 128 rows.
//  - A: float4 z loads (32/thread), in-thread octet assembly,
//       16 ds_write_b128 to swizzled fragment LDS, then A -> 32 regs/wave
//  - B: 16 chunks x 64 codes, dbuf linear global_load_lds (unchanged)
//  - epilogue: f32 ef [64][258] x2 passes, float4 stores
// LDS (72768 B, 2 blocks/CU):
//   region0 [0,66048): A-scratch(64K) / B dbuf(64K) / ef f32 64x258 (66048)
//   hn [66048,70144) lv [70144,71168) li [71168,72192)
//   idx [72192,72704) red [72704,72768)
// =====================================================================
#define HN_OFF   66048
#define LV_OFF   70144
#define LI_OFF   71168
#define IDX_OFF  72192
#define RED_OFF  72704
#define LDS_SZ   72768

__global__ __launch_bounds__(256, 2) void k1_fused(const float* __restrict__ z,
                                                   const float* __restrict__ cb,
                                                   const char* __restrict__ cbb,
                                                   const float* __restrict__ hn,
                                                   float* __restrict__ out,
                                                   float* __restrict__ pz2,
                                                   float* __restrict__ ps) {
  extern __shared__ char smem[];
  const int t = threadIdx.x, w = t >> 6, lane = t & 63;
  const int l15 = lane & 15, g4 = lane >> 4;
  const int wr = w >> 1, wc = w & 1;
  const int bid = blockIdx.x;
  const int b = bid >> 5, hw0 = (bid & 31) << 7;
  const float* zb = z + ((size_t)b << 20) + hw0;

  // ---- A stage: float4 z loads -> swizzled fragment-order LDS ----
  // thread: hw quad q (rows q*4..q*4+3), octet-slot oo; 4 passes over octets.
  const int q = lane & 31;
  const int oo = (w << 1) + (lane >> 5);
  const int band = q >> 4, mb_w = (q >> 2) & 3, r4 = (q & 3) * 4;
  float ss = 0.f;
#pragma unroll
  for (int p = 0; p < 4; ++p) {
    const int o = p * 8 + oo;  // channel octet 0..31
    float4 v[8];
#pragma unroll
    for (int j = 0; j < 8; ++j)
      v[j] = *(const float4*)(zb + (size_t)(o * 8 + j) * 4096 + q * 4);
#pragma unroll
    for (int j = 0; j < 8; ++j)
      ss += v[j].x * v[j].x + v[j].y * v[j].y + v[j].z * v[j].z + v[j].w * v[j].w;
    const int kk = o >> 2, g = o & 3;
    char* base = smem + band * 32768 + ((mb_w * 8 + kk) << 10);
#pragma unroll
    for (int k = 0; k < 4; ++k) {
      uint4 q4;
      q4.x = f2bf(((const float*)&v[0])[k]) | (f2bf(((const float*)&v[1])[k]) << 16);
      q4.y = f2bf(((const float*)&v[2])[k]) | (f2bf(((const float*)&v[3])[k]) << 16);
      q4.z = f2bf(((const float*)&v[4])[k]) | (f2bf(((const float*)&v[5])[k]) << 16);
      q4.w = f2bf(((const float*)&v[6])[k]) | (f2bf(((const float*)&v[7])[k]) << 16);
      *(uint4*)(base + ((g * 16 + r4 + (k ^ mb_w)) << 4)) = q4;
    }
  }
  // hn -> LDS (1024 floats)
  *(float4*)(smem + HN_OFF + t * 16) = *(const float4*)(hn + 4 * t);
  __syncthreads();

  // ---- A panel -> registers (held for all 16 chunks) ----
  bf16x8 A[4][8];
#pragma unroll
  for (int mb = 0; mb < 4; ++mb)
#pragma unroll
    for (int kk = 0; kk < 8; ++kk)
      A[mb][kk] = *(const bf16x8*)(smem + wr * 32768 + ((mb * 8 + kk) << 10) +
                   ((g4 * 16 + (l15 & 12) + ((l15 & 3) ^ mb)) << 4));
  __syncthreads();  // scratch reads done before B staging overwrites

  // ---- B chunk stage: linear copy (cbb already fragment-ordered) ----
  auto stageB = [&](int buf, int ch) {
#pragma unroll
    for (int i = 0; i < 8; ++i) {
      __builtin_amdgcn_global_load_lds(
          (const __attribute__((address_space(1))) unsigned int*)
              (cbb + (size_t)ch * 32768 + i * 4096 + w * 1024 + lane * 16),
          (__attribute__((address_space(3))) unsigned int*)
              (smem + buf * 32768 + i * 4096 + w * 1024),
          16, 0, 0);
    }
  };
  stageB(0, 0);

  float bestv[4][4];
  int besti[4][4];
#pragma unroll
  for (int m = 0; m < 4; ++m)
#pragma unroll
    for (int i = 0; i < 4; ++i) { bestv[m][i] = -3.4e38f; besti[m][i] = 0; }

  __syncthreads();  // buf0 staged

  // ---- main loop: 16 chunks x 64 codes (unchanged, verified) ----
  for (int ch = 0; ch < 16; ++ch) {
    const int cur = ch & 1;
    if (ch < 15) stageB(cur ^ 1, ch + 1);
    const float hnv0 = *(const float*)(smem + HN_OFF + (ch * 64 + wc * 32 + l15) * 4);
    const float hnv1 = *(const float*)(smem + HN_OFF + (ch * 64 + wc * 32 + 16 + l15) * 4);
    f32x4v acc[4][2];
#pragma unroll
    for (int m = 0; m < 4; ++m)
#pragma unroll
      for (int n = 0; n < 2; ++n) acc[m][n] = (f32x4v){0.f, 0.f, 0.f, 0.f};
#pragma unroll
    for (int kk = 0; kk < 8; ++kk) {
      const bf16x8 b0 = *(const bf16x8*)(smem + cur * 32768 +
                        (((wc * 2 + 0) * 8 + kk) << 10) + (lane << 4));
      const bf16x8 b1 = *(const bf16x8*)(smem + cur * 32768 +
                        (((wc * 2 + 1) * 8 + kk) << 10) + (lane << 4));
#pragma unroll
      for (int m = 0; m < 4; ++m) {
        acc[m][0] = __builtin_amdgcn_mfma_f32_16x16x32_bf16(A[m][kk], b0, acc[m][0], 0, 0, 0);
        acc[m][1] = __builtin_amdgcn_mfma_f32_16x16x32_bf16(A[m][kk], b1, acc[m][1], 0, 0, 0);
      }
    }
#pragma unroll
    for (int m = 0; m < 4; ++m)
#pragma unroll
      for (int n = 0; n < 2; ++n) {
        const int col = ch * 64 + wc * 32 + n * 16 + l15;
        const float hv = n ? hnv1 : hnv0;
#pragma unroll
        for (int i = 0; i < 4; ++i) {
          const float vv = acc[m][n][i] - hv;
          if (vv > bestv[m][i]) { bestv[m][i] = vv; besti[m][i] = col; }
        }
      }
    __syncthreads();
  }

  // ---- cross-lane argmax within 16-col groups ----
#pragma unroll
  for (int m = 0; m < 4; ++m)
#pragma unroll
    for (int i = 0; i < 4; ++i) {
      float v = bestv[m][i];
      int ix = besti[m][i];
#pragma unroll
      for (int s = 1; s < 16; s <<= 1) {
        const float ov = __shfl_xor(v, s, 64);
        const int oi = __shfl_xor(ix, s, 64);
        if (ov > v || (ov == v && oi < ix)) { v = ov; ix = oi; }
      }
      bestv[m][i] = v; besti[m][i] = ix;
    }

  float* lv = (float*)(smem + LV_OFF);
  int* li = (int*)(smem + LI_OFF);
  int* idx_s = (int*)(smem + IDX_OFF);
  if (l15 == 0) {
#pragma unroll
    for (int m = 0; m < 4; ++m)
#pragma unroll
      for (int i = 0; i < 4; ++i) {
        const int row = wr * 64 + m * 16 + g4 * 4 + i;
        lv[wc * 128 + row] = bestv[m][i];
        li[wc * 128 + row] = besti[m][i];
      }
  }
  __syncthreads();
  float sv = 0.f;
  if (t < 128) {
    const float v0 = lv[t], v1 = lv[128 + t];
    const int i0 = li[t], i1 = li[128 + t];
    const bool take1 = (v1 > v0) || (v1 == v0 && i1 < i0);
    sv = take1 ? v1 : v0;
    idx_s[t] = take1 ? i1 : i0;
  }
  // block reductions: pz2 = Sigma z^2 (exact cover), ps = Sigma s*
  float zz = ss;
#pragma unroll
  for (int s = 32; s; s >>= 1) {
    zz += __shfl_down(zz, s, 64);
    sv += __shfl_down(sv, s, 64);
  }
  float* red = (float*)(smem + RED_OFF);
  if (lane == 0) { red[w] = zz; red[4 + w] = sv; }
  __syncthreads();  // idx_s visible; B bufs dead -> ef may overlay
  if (t == 0) {
    pz2[bid] = red[0] + red[1] + red[2] + red[3];
    ps[bid] = red[4] + red[5] + red[6] + red[7];
  }

  // ---- epilogue: 2 passes of 64 rows, f32 ef [64][258], float4 stores ----
  const int q2 = lane & 15, cs = lane >> 4;
  for (int h = 0; h < 2; ++h) {
    __syncthreads();  // prev pass reads done (h=0: red/idx sync above)
#pragma unroll 4
    for (int rr = 0; rr < 16; ++rr) {
      const int r = h * 64 + w * 16 + rr;
      const int code = idx_s[r];  // wave-uniform broadcast
      const float4 ev = *(const float4*)(cb + (size_t)code * 256 + lane * 4);
      char* dst = smem + (w * 16 + rr) * 1032 + lane * 16;
      *(float2*)dst = (float2){ev.x, ev.y};
      *(float2*)(dst + 8) = (float2){ev.z, ev.w};
    }
    __syncthreads();
    float* outb = out + ((size_t)b << 20) + hw0 + h * 64;
#pragma unroll 4
    for (int i = 0; i < 16; ++i) {
      const int c = w * 64 + i * 4 + cs;
      float4 ov;
      ov.x = *(const float*)(smem + (q2 * 4 + 0) * 1032 + c * 4);
      ov.y = *(const float*)(smem + (q2 * 4 + 1) * 1032 + c * 4);
      ov.z = *(const float*)(smem + (q2 * 4 + 2) * 1032 + c * 4);
      ov.w = *(const float*)(smem + (q2 * 4 + 3) * 1032 + c * 4);
      *(float4*)(outb + (size_t)c * 4096 + q2 * 4) = ov;
    }
  }
}

// =====================================================================
// k3: deterministic reduce of 512 block partials -> vq_loss
// =====================================================================
__global__ __launch_bounds__(256) void k3_loss(const float* __restrict__ pz2,
                                               const float* __restrict__ ps,
                                               float* __restrict__ loss_out) {
  __shared__ double red[256];
  const int t = threadIdx.x;
  double s = ((double)pz2[t] - 2.0 * (double)ps[t]) +
             ((double)pz2[t + 256] - 2.0 * (double)ps[t + 256]);
  red[t] = s;
  __syncthreads();
  for (int st = 128; st; st >>= 1) {
    if (t < st) red[t] += red[t + st];
    __syncthreads();
  }
  if (t == 0) loss_out[0] = (float)(red[0] * (1.25 / 16777216.0));
}

// =====================================================================
extern "C" void kernel_launch(void* const* d_in, const int* in_sizes, int n_in,
                              void* d_out, int out_size, void* d_ws, size_t ws_size,
                              hipStream_t stream) {
  (void)in_sizes; (void)n_in; (void)out_size; (void)ws_size;
  const float* z = (const float*)d_in[0];
  const float* cb = (const float*)d_in[1];
  float* out = (float*)d_out;

  char* wsb = (char*)d_ws;
  char* cbb = wsb;                               // 524288 B (fragment-ordered bf16)
  float* hn = (float*)(wsb + 524288);            //   4096 B
  float* pz2 = (float*)(wsb + 528384);           //   2048 B
  float* ps = (float*)(wsb + 530432);            //   2048 B

  (void)hipFuncSetAttribute((const void*)k1_fused,
                            hipFuncAttributeMaxDynamicSharedMemorySize, LDS_SZ);

  k0b_cb<<<dim3(1024), dim3(64), 0, stream>>>(cb, cbb, hn);
  k1_fused<<<dim3(512), dim3(256), LDS_SZ, stream>>>(z, cb, cbb, hn, out, pz2, ps);
  k3_loss<<<dim3(1), dim3(256), 0, stream>>>(pz2, ps, out + 16777216);
}

// Round 6
// 69.692 us; speedup vs baseline: 1.3345x; 1.3345x over previous
//
#include <hip/hip_runtime.h>
#include <stdint.h>

using bf16x8 = __attribute__((ext_vector_type(8))) __bf16;
using f32x4v = __attribute__((ext_vector_type(4))) float;

__device__ __forceinline__ unsigned int f2bf(float f) {
  unsigned int u = __float_as_uint(f);
  return (u + 0x7FFFu + ((u >> 16) & 1u)) >> 16;  // RNE f32->bf16
}

// =====================================================================
// k0b: codebook f32 [1024][256] -> bf16 in MFMA FRAGMENT order + 0.5||e||^2
// (verified R4)
// =====================================================================
__global__ __launch_bounds__(64) void k0b_cb(const float* __restrict__ cb,
                                             char* __restrict__ cbb,
                                             float* __restrict__ hn) {
  const int code = blockIdx.x, l = threadIdx.x;
  const float4 v = *(const float4*)(cb + code * 256 + l * 4);
  float ss = v.x * v.x + v.y * v.y + v.z * v.z + v.w * v.w;
  uint2 p;
  p.x = f2bf(v.x) | (f2bf(v.y) << 16);
  p.y = f2bf(v.z) | (f2bf(v.w) << 16);
  const int addr = (((code >> 4) * 8 + (l >> 3)) << 10) +
                   ((((l & 7) >> 1) * 16 + (code & 15)) << 4) + (l & 1) * 8;
  *(uint2*)(cbb + addr) = p;
#pragma unroll
  for (int s = 32; s; s >>= 1) ss += __shfl_down(ss, s, 64);
  if (l == 0) hn[code] = 0.5f * ss;
}

// =====================================================================
// k1_fused: 512 blocks x 256 thr (4 waves), block = 128 rows (one b,
// 128 consecutive hw). Waves: wr=w>>1 row-band (64 rows), wc=w&1 chan half.
// EXACT R4 structure (verified 65.2 us) + non-temporal z loads / out stores
// (streaming 16 MB/XCD was thrashing the 4 MB L2 that cbb DMA depends on).
// LDS (72768 B => 2 blocks/CU):
//   B buf0 [0,32768) buf1 [32768,65536)   (A-stage scratch reuses [0,65536))
//   ef overlay [0,66048) bf16[128][258]
//   hn [66048,70144) lv [70144,71168) li [71168,72192)
//   idx [72192,72704) red [72704,72768)
// =====================================================================
#define HN_OFF   66048
#define LV_OFF   70144
#define LI_OFF   71168
#define IDX_OFF  72192
#define RED_OFF  72704
#define LDS_SZ   72768

__global__ __launch_bounds__(256, 2) void k1_fused(const float* __restrict__ z,
                                                   const float* __restrict__ cb,
                                                   const char* __restrict__ cbb,
                                                   const float* __restrict__ hn,
                                                   float* __restrict__ out,
                                                   float* __restrict__ pz2,
                                                   float* __restrict__ ps) {
  extern __shared__ char smem[];
  const int t = threadIdx.x, w = t >> 6, lane = t & 63;
  const int l15 = lane & 15, g4 = lane >> 4;
  const int wr = w >> 1, wc = w & 1;
  const int bid = blockIdx.x;
  const int b = bid >> 5, hw0 = (bid & 31) << 7;

  // ---- A stage: z NCHW f32 -> frag-order LDS scratch (band-cooperative) ----
  // wave (wr,wc): rows = band wr (row = lane), channels wc*128 .. +128.
  const float* zw = z + ((size_t)b << 20) + hw0 + wr * 64 + lane;
  float ss = 0.f;
#pragma unroll 4
  for (int grp = 0; grp < 16; ++grp) {
    float f[8];
#pragma unroll
    for (int j = 0; j < 8; ++j)
      f[j] = __builtin_nontemporal_load(&zw[(size_t)(wc * 128 + grp * 8 + j) * 4096]);
#pragma unroll
    for (int j = 0; j < 8; ++j) ss += f[j] * f[j];
    uint4 q;
    q.x = f2bf(f[0]) | (f2bf(f[1]) << 16);
    q.y = f2bf(f[2]) | (f2bf(f[3]) << 16);
    q.z = f2bf(f[4]) | (f2bf(f[5]) << 16);
    q.w = f2bf(f[6]) | (f2bf(f[7]) << 16);
    const int kk = wc * 4 + (grp >> 2), g = grp & 3;
    const int geff = (g + g4) & 3;  // rotate to spread write banks
    *(uint4*)(smem + wr * 32768 + ((g4 * 8 + kk) << 10) + ((geff * 16 + l15) << 4)) = q;
  }
  // hn -> LDS (1024 floats)
  *(float4*)(smem + HN_OFF + t * 16) = *(const float4*)(hn + 4 * t);
  __syncthreads();

  // ---- A panel -> registers (held for all 16 chunks) ----
  bf16x8 A[4][8];
#pragma unroll
  for (int mb = 0; mb < 4; ++mb)
#pragma unroll
    for (int kk = 0; kk < 8; ++kk) {
      const int geff = (g4 + mb) & 3;
      A[mb][kk] = *(const bf16x8*)(smem + wr * 32768 + ((mb * 8 + kk) << 10) +
                                   ((geff * 16 + l15) << 4));
    }
  __syncthreads();  // scratch reads done before B staging overwrites

  // ---- B chunk stage: linear copy (cbb already fragment-ordered) ----
  auto stageB = [&](int buf, int ch) {
#pragma unroll
    for (int i = 0; i < 8; ++i) {
      __builtin_amdgcn_global_load_lds(
          (const __attribute__((address_space(1))) unsigned int*)
              (cbb + (size_t)ch * 32768 + i * 4096 + w * 1024 + lane * 16),
          (__attribute__((address_space(3))) unsigned int*)
              (smem + buf * 32768 + i * 4096 + w * 1024),
          16, 0, 0);
    }
  };
  stageB(0, 0);

  float bestv[4][4];
  int besti[4][4];
#pragma unroll
  for (int m = 0; m < 4; ++m)
#pragma unroll
    for (int i = 0; i < 4; ++i) { bestv[m][i] = -3.4e38f; besti[m][i] = 0; }

  __syncthreads();  // buf0 staged (syncthreads drains vmcnt)

  // ---- main loop: 16 chunks x 64 codes (verified) ----
  for (int ch = 0; ch < 16; ++ch) {
    const int cur = ch & 1;
    if (ch < 15) stageB(cur ^ 1, ch + 1);
    const float hnv0 = *(const float*)(smem + HN_OFF + (ch * 64 + wc * 32 + l15) * 4);
    const float hnv1 = *(const float*)(smem + HN_OFF + (ch * 64 + wc * 32 + 16 + l15) * 4);
    f32x4v acc[4][2];
#pragma unroll
    for (int m = 0; m < 4; ++m)
#pragma unroll
      for (int n = 0; n < 2; ++n) acc[m][n] = (f32x4v){0.f, 0.f, 0.f, 0.f};
#pragma unroll
    for (int kk = 0; kk < 8; ++kk) {
      const bf16x8 b0 = *(const bf16x8*)(smem + cur * 32768 +
                        (((wc * 2 + 0) * 8 + kk) << 10) + (lane << 4));
      const bf16x8 b1 = *(const bf16x8*)(smem + cur * 32768 +
                        (((wc * 2 + 1) * 8 + kk) << 10) + (lane << 4));
#pragma unroll
      for (int m = 0; m < 4; ++m) {
        acc[m][0] = __builtin_amdgcn_mfma_f32_16x16x32_bf16(A[m][kk], b0, acc[m][0], 0, 0, 0);
        acc[m][1] = __builtin_amdgcn_mfma_f32_16x16x32_bf16(A[m][kk], b1, acc[m][1], 0, 0, 0);
      }
    }
#pragma unroll
    for (int m = 0; m < 4; ++m)
#pragma unroll
      for (int n = 0; n < 2; ++n) {
        const int col = ch * 64 + wc * 32 + n * 16 + l15;
        const float hv = n ? hnv1 : hnv0;
#pragma unroll
        for (int i = 0; i < 4; ++i) {
          const float vv = acc[m][n][i] - hv;
          if (vv > bestv[m][i]) { bestv[m][i] = vv; besti[m][i] = col; }
        }
      }
    __syncthreads();
  }

  // ---- cross-lane argmax within 16-col groups ----
#pragma unroll
  for (int m = 0; m < 4; ++m)
#pragma unroll
    for (int i = 0; i < 4; ++i) {
      float v = bestv[m][i];
      int ix = besti[m][i];
#pragma unroll
      for (int s = 1; s < 16; s <<= 1) {
        const float ov = __shfl_xor(v, s, 64);
        const int oi = __shfl_xor(ix, s, 64);
        if (ov > v || (ov == v && oi < ix)) { v = ov; ix = oi; }
      }
      bestv[m][i] = v; besti[m][i] = ix;
    }

  float* lv = (float*)(smem + LV_OFF);
  int* li = (int*)(smem + LI_OFF);
  int* idx_s = (int*)(smem + IDX_OFF);
  if (l15 == 0) {
#pragma unroll
    for (int m = 0; m < 4; ++m)
#pragma unroll
      for (int i = 0; i < 4; ++i) {
        const int row = wr * 64 + m * 16 + g4 * 4 + i;
        lv[wc * 128 + row] = bestv[m][i];
        li[wc * 128 + row] = besti[m][i];
      }
  }
  __syncthreads();
  float sv = 0.f;
  if (t < 128) {
    const float v0 = lv[t], v1 = lv[128 + t];
    const int i0 = li[t], i1 = li[128 + t];
    const bool take1 = (v1 > v0) || (v1 == v0 && i1 < i0);
    sv = take1 ? v1 : v0;
    idx_s[t] = take1 ? i1 : i0;
  }
  // block reductions: pz2 = Sigma z^2 (exact cover), ps = Sigma s*
  float zz = ss;
#pragma unroll
  for (int s = 32; s; s >>= 1) {
    zz += __shfl_down(zz, s, 64);
    sv += __shfl_down(sv, s, 64);
  }
  float* red = (float*)(smem + RED_OFF);
  if (lane == 0) { red[w] = zz; red[4 + w] = sv; }
  __syncthreads();  // idx_s visible; B bufs dead -> ef may overlay
  if (t == 0) {
    pz2[bid] = red[0] + red[1] + red[2] + red[3];
    ps[bid] = red[4] + red[5] + red[6] + red[7];
  }

  // ---- epilogue: chosen rows -> bf16 LDS [128][258] -> NCHW out (R4) ----
#pragma unroll 4
  for (int rr = 0; rr < 32; ++rr) {
    const int r = w * 32 + rr;
    const int code = idx_s[r];  // wave-uniform broadcast
    const float4 ev = *(const float4*)(cb + (size_t)code * 256 + lane * 4);
    uint2 p;
    p.x = f2bf(ev.x) | (f2bf(ev.y) << 16);
    p.y = f2bf(ev.z) | (f2bf(ev.w) << 16);
    *(uint2*)(smem + r * 516 + lane * 8) = p;
  }
  __syncthreads();
  float* outb = out + ((size_t)b << 20) + hw0;
#pragma unroll 4
  for (int cc = 0; cc < 64; ++cc) {
    const int c = w * 64 + cc;
#pragma unroll
    for (int h = 0; h < 2; ++h) {
      const int row = h * 64 + lane;
      const ushort u = *(const ushort*)(smem + row * 516 + c * 2);
      __builtin_nontemporal_store(__uint_as_float(((unsigned)u) << 16),
                                  &outb[(size_t)c * 4096 + row]);
    }
  }
}

// =====================================================================
// k3: deterministic reduce of 512 block partials -> vq_loss
// =====================================================================
__global__ __launch_bounds__(256) void k3_loss(const float* __restrict__ pz2,
                                               const float* __restrict__ ps,
                                               float* __restrict__ loss_out) {
  __shared__ double red[256];
  const int t = threadIdx.x;
  double s = ((double)pz2[t] - 2.0 * (double)ps[t]) +
             ((double)pz2[t + 256] - 2.0 * (double)ps[t + 256]);
  red[t] = s;
  __syncthreads();
  for (int st = 128; st; st >>= 1) {
    if (t < st) red[t] += red[t + st];
    __syncthreads();
  }
  if (t == 0) loss_out[0] = (float)(red[0] * (1.25 / 16777216.0));
}

// =====================================================================
extern "C" void kernel_launch(void* const* d_in, const int* in_sizes, int n_in,
                              void* d_out, int out_size, void* d_ws, size_t ws_size,
                              hipStream_t stream) {
  (void)in_sizes; (void)n_in; (void)out_size; (void)ws_size;
  const float* z = (const float*)d_in[0];
  const float* cb = (const float*)d_in[1];
  float* out = (float*)d_out;

  char* wsb = (char*)d_ws;
  char* cbb = wsb;                               // 524288 B (fragment-ordered bf16)
  float* hn = (float*)(wsb + 524288);            //   4096 B
  float* pz2 = (float*)(wsb + 528384);           //   2048 B
  float* ps = (float*)(wsb + 530432);            //   2048 B

  (void)hipFuncSetAttribute((const void*)k1_fused,
                            hipFuncAttributeMaxDynamicSharedMemorySize, LDS_SZ);

  k0b_cb<<<dim3(1024), dim3(64), 0, stream>>>(cb, cbb, hn);
  k1_fused<<<dim3(512), dim3(256), LDS_SZ, stream>>>(z, cb, cbb, hn, out, pz2, ps);
  k3_loss<<<dim3(1), dim3(256), 0, stream>>>(pz2, ps, out + 16777216);
}

// Round 8
// 68.950 us; speedup vs baseline: 1.3489x; 1.0108x over previous
//
#include <hip/hip_runtime.h>
#include <stdint.h>

using bf16x8 = __attribute__((ext_vector_type(8))) __bf16;
using f32x4v = __attribute__((ext_vector_type(4))) float;

__device__ __forceinline__ unsigned int f2bf(float f) {
  unsigned int u = __float_as_uint(f);
  return (u + 0x7FFFu + ((u >> 16) & 1u)) >> 16;  // RNE f32->bf16
}

// =====================================================================
// k0b: codebook f32 [1024][256] -> bf16 in MFMA FRAGMENT order, grouped in
// 32-code chunks (16 KB each): addr = (code>>5)*16384
//   + (((code>>4)&1)*8 + kk)*1024 + (g*16 + (code&15))*16 + j*2
// thread l covers ch l*4..l*4+3: kk=l>>3, g=(l>>1)&3, j2=(l&1)*4+cc.
// Also hn = 0.5*||e||^2.
// =====================================================================
__global__ __launch_bounds__(64) void k0b_cb(const float* __restrict__ cb,
                                             char* __restrict__ cbb,
                                             float* __restrict__ hn) {
  const int code = blockIdx.x, l = threadIdx.x;
  const float4 v = *(const float4*)(cb + code * 256 + l * 4);
  float ss = v.x * v.x + v.y * v.y + v.z * v.z + v.w * v.w;
  uint2 p;
  p.x = f2bf(v.x) | (f2bf(v.y) << 16);
  p.y = f2bf(v.z) | (f2bf(v.w) << 16);
  const int addr = ((code >> 5) << 14) +
                   (((((code >> 4) & 1) << 3) + (l >> 3)) << 10) +
                   (((((l >> 1) & 3) << 4) + (code & 15)) << 4) + (l & 1) * 8;
  *(uint2*)(cbb + addr) = p;
#pragma unroll
  for (int s = 32; s; s >>= 1) ss += __shfl_down(ss, s, 64);
  if (l == 0) hn[code] = 0.5f * ss;
}

// =====================================================================
// k1_fused: 1024 blocks x 256 thr (4 waves), block = 64 rows (one b, 64
// consecutive hw). Waves: wr=w>>1 row-band (32 rows), wc=w&1 code half.
// Wave tile M=32: A regs = 16 bf16x8 = 64 VGPR -> 4 waves/SIMD;
// LDS 38464 -> 4 blocks/CU => 16 waves/CU.
//  - A: float4 z loads -> frag-order LDS scratch [2 bands x 16KB] -> regs
//  - B: 32 chunks x 32 codes, dbuf 2x16KB global_load_lds
//    (NOTE: global_load_lds writes base+lane*16 per WAVE issue = 1KB;
//     a 16KB chunk needs 4 issues/wave x 4 waves  [R7 bug: 1 issue/wave
//     staged only 1/4, leaving z data in B -> loss corrupt])
//  - per chunk/wave: 8 ds_read_b128 + 16 MFMA
//  - epilogue: gather rows -> bf16 ef [64][258] -> NCHW float stores
// LDS map (38464 B):
//   region0 [0,33024): A-scratch 32K / B dbuf 2x16K / ef bf16[64][258]
//   hn [33024,37120) lv [37120,37632) li [37632,38144)
//   idx [38144,38400) red [38400,38464)
// =====================================================================
#define HN_OFF   33024
#define LV_OFF   37120
#define LI_OFF   37632
#define IDX_OFF  38144
#define RED_OFF  38400
#define LDS_SZ   38464

__global__ __launch_bounds__(256, 4) void k1_fused(const float* __restrict__ z,
                                                   const float* __restrict__ cb,
                                                   const char* __restrict__ cbb,
                                                   const float* __restrict__ hn,
                                                   float* __restrict__ out,
                                                   float* __restrict__ pz2,
                                                   float* __restrict__ ps) {
  extern __shared__ char smem[];
  const int t = threadIdx.x, w = t >> 6, lane = t & 63;
  const int l15 = lane & 15, g4 = lane >> 4;
  const int wr = w >> 1, wc = w & 1;
  const int bid = blockIdx.x;
  const int b = bid >> 6, hw0 = (bid & 63) << 6;
  const float* zb = z + ((size_t)b << 20) + hw0;

  // ---- A stage: 64 rows x 256 ch, float4 loads, frag-order LDS writes ----
  // thread: row-quad q = t&15 (rows q*4..+3), octet slots oslot, oslot+16.
  const int q = t & 15, oslot = t >> 4;
  float ss = 0.f;
#pragma unroll 1
  for (int oi = 0; oi < 2; ++oi) {
    const int o = oslot + oi * 16;  // channel octet 0..31
    float4 f[8];
#pragma unroll
    for (int j = 0; j < 8; ++j)
      f[j] = *(const float4*)(zb + (size_t)(o * 8 + j) * 4096 + q * 4);
#pragma unroll
    for (int j = 0; j < 8; ++j)
      ss += f[j].x * f[j].x + f[j].y * f[j].y + f[j].z * f[j].z + f[j].w * f[j].w;
    const int kk = o >> 2, g = o & 3;
#pragma unroll
    for (int k = 0; k < 4; ++k) {
      const int row = q * 4 + k;
      const int band = row >> 5, rb = row & 31;
      const int mb = rb >> 4, r15 = rb & 15;
      uint4 q4;
      q4.x = f2bf(((const float*)&f[0])[k]) | (f2bf(((const float*)&f[1])[k]) << 16);
      q4.y = f2bf(((const float*)&f[2])[k]) | (f2bf(((const float*)&f[3])[k]) << 16);
      q4.z = f2bf(((const float*)&f[4])[k]) | (f2bf(((const float*)&f[5])[k]) << 16);
      q4.w = f2bf(((const float*)&f[6])[k]) | (f2bf(((const float*)&f[7])[k]) << 16);
      *(uint4*)(smem + (band << 14) + (((mb << 3) + kk) << 10) + (((g << 4) + r15) << 4)) = q4;
    }
  }
  // hn -> LDS (1024 floats)
  *(float4*)(smem + HN_OFF + t * 16) = *(const float4*)(hn + 4 * t);
  __syncthreads();

  // ---- A panel -> registers (16 frags = 64 VGPR) ----
  bf16x8 A[2][8];
#pragma unroll
  for (int mb = 0; mb < 2; ++mb)
#pragma unroll
    for (int kk = 0; kk < 8; ++kk)
      A[mb][kk] = *(const bf16x8*)(smem + (wr << 14) + (((mb << 3) + kk) << 10) + (lane << 4));
  __syncthreads();  // scratch reads done before B staging overwrites

  // ---- B chunk stage: 16 KB = 4 issues/wave x 1 KB x 4 waves ----
  auto stageB = [&](int buf, int ch) {
#pragma unroll
    for (int i = 0; i < 4; ++i) {
      __builtin_amdgcn_global_load_lds(
          (const __attribute__((address_space(1))) unsigned int*)
              (cbb + ((size_t)ch << 14) + (w << 12) + (i << 10) + (lane << 4)),
          (__attribute__((address_space(3))) unsigned int*)
              (smem + (buf << 14) + (w << 12) + (i << 10)),
          16, 0, 0);
    }
  };
  stageB(0, 0);

  float bestv[2][4];
  int besti[2][4];
#pragma unroll
  for (int m = 0; m < 2; ++m)
#pragma unroll
    for (int i = 0; i < 4; ++i) { bestv[m][i] = -3.4e38f; besti[m][i] = 0; }

  __syncthreads();  // buf0 staged (syncthreads drains vmcnt)

  // ---- main loop: 32 chunks x 32 codes ----
  for (int ch = 0; ch < 32; ++ch) {
    const int cur = ch & 1;
    if (ch < 31) stageB(cur ^ 1, ch + 1);
    const int col = ch * 32 + wc * 16 + l15;
    const float hnv = *(const float*)(smem + HN_OFF + col * 4);
    f32x4v acc[2];
    acc[0] = (f32x4v){0.f, 0.f, 0.f, 0.f};
    acc[1] = (f32x4v){0.f, 0.f, 0.f, 0.f};
#pragma unroll
    for (int kk = 0; kk < 8; ++kk) {
      const bf16x8 b0 = *(const bf16x8*)(smem + (cur << 14) +
                        ((((wc << 3) + kk)) << 10) + (lane << 4));
      acc[0] = __builtin_amdgcn_mfma_f32_16x16x32_bf16(A[0][kk], b0, acc[0], 0, 0, 0);
      acc[1] = __builtin_amdgcn_mfma_f32_16x16x32_bf16(A[1][kk], b0, acc[1], 0, 0, 0);
    }
#pragma unroll
    for (int m = 0; m < 2; ++m)
#pragma unroll
      for (int i = 0; i < 4; ++i) {
        const float vv = acc[m][i] - hnv;
        if (vv > bestv[m][i]) { bestv[m][i] = vv; besti[m][i] = col; }
      }
    __syncthreads();  // next chunk staged + all waves done with buf[cur]
  }

  // ---- cross-lane argmax within 16-col groups ----
#pragma unroll
  for (int m = 0; m < 2; ++m)
#pragma unroll
    for (int i = 0; i < 4; ++i) {
      float v = bestv[m][i];
      int ix = besti[m][i];
#pragma unroll
      for (int s = 1; s < 16; s <<= 1) {
        const float ov = __shfl_xor(v, s, 64);
        const int oi = __shfl_xor(ix, s, 64);
        if (ov > v || (ov == v && oi < ix)) { v = ov; ix = oi; }
      }
      bestv[m][i] = v; besti[m][i] = ix;
    }

  float* lv = (float*)(smem + LV_OFF);
  int* li = (int*)(smem + LI_OFF);
  int* idx_s = (int*)(smem + IDX_OFF);
  if (l15 == 0) {
#pragma unroll
    for (int m = 0; m < 2; ++m)
#pragma unroll
      for (int i = 0; i < 4; ++i) {
        const int row = wr * 32 + m * 16 + g4 * 4 + i;
        lv[wc * 64 + row] = bestv[m][i];
        li[wc * 64 + row] = besti[m][i];
      }
  }
  __syncthreads();
  float sv = 0.f;
  if (t < 64) {
    const float v0 = lv[t], v1 = lv[64 + t];
    const int i0 = li[t], i1 = li[64 + t];
    const bool take1 = (v1 > v0) || (v1 == v0 && i1 < i0);
    sv = take1 ? v1 : v0;
    idx_s[t] = take1 ? i1 : i0;
  }
  // block reductions: pz2 = Sigma z^2 (exact cover), ps = Sigma s*
  float zz = ss;
#pragma unroll
  for (int s = 32; s; s >>= 1) {
    zz += __shfl_down(zz, s, 64);
    sv += __shfl_down(sv, s, 64);
  }
  float* red = (float*)(smem + RED_OFF);
  if (lane == 0) { red[w] = zz; red[4 + w] = sv; }
  __syncthreads();  // idx_s visible; scratch/B dead -> ef may overlay
  if (t == 0) {
    pz2[bid] = red[0] + red[1] + red[2] + red[3];
    ps[bid] = red[4] + red[5] + red[6] + red[7];
  }

  // ---- epilogue: chosen rows -> bf16 ef [64][258] -> NCHW out ----
#pragma unroll 4
  for (int rr = 0; rr < 16; ++rr) {
    const int r = w * 16 + rr;
    const int code = idx_s[r];  // wave-uniform broadcast
    const float4 ev = *(const float4*)(cb + (size_t)code * 256 + lane * 4);
    uint2 p;
    p.x = f2bf(ev.x) | (f2bf(ev.y) << 16);
    p.y = f2bf(ev.z) | (f2bf(ev.w) << 16);
    *(uint2*)(smem + r * 516 + lane * 8) = p;
  }
  __syncthreads();
  float* outb = out + ((size_t)b << 20) + hw0;
#pragma unroll 4
  for (int cc = 0; cc < 64; ++cc) {
    const int c = w * 64 + cc;
    const ushort u = *(const ushort*)(smem + lane * 516 + c * 2);
    __builtin_nontemporal_store(__uint_as_float(((unsigned)u) << 16),
                                &outb[(size_t)c * 4096 + lane]);
  }
}

// =====================================================================
// k3: deterministic reduce of 1024 block partials -> vq_loss
// =====================================================================
__global__ __launch_bounds__(256) void k3_loss(const float* __restrict__ pz2,
                                               const float* __restrict__ ps,
                                               float* __restrict__ loss_out) {
  __shared__ double red[256];
  const int t = threadIdx.x;
  double s = 0.0;
#pragma unroll
  for (int i = 0; i < 4; ++i)
    s += (double)pz2[t * 4 + i] - 2.0 * (double)ps[t * 4 + i];
  red[t] = s;
  __syncthreads();
  for (int st = 128; st; st >>= 1) {
    if (t < st) red[t] += red[t + st];
    __syncthreads();
  }
  if (t == 0) loss_out[0] = (float)(red[0] * (1.25 / 16777216.0));
}

// =====================================================================
extern "C" void kernel_launch(void* const* d_in, const int* in_sizes, int n_in,
                              void* d_out, int out_size, void* d_ws, size_t ws_size,
                              hipStream_t stream) {
  (void)in_sizes; (void)n_in; (void)out_size; (void)ws_size;
  const float* z = (const float*)d_in[0];
  const float* cb = (const float*)d_in[1];
  float* out = (float*)d_out;

  char* wsb = (char*)d_ws;
  char* cbb = wsb;                               // 524288 B (fragment-ordered bf16)
  float* hn = (float*)(wsb + 524288);            //   4096 B
  float* pz2 = (float*)(wsb + 528384);           //   4096 B
  float* ps = (float*)(wsb + 532480);            //   4096 B

  (void)hipFuncSetAttribute((const void*)k1_fused,
                            hipFuncAttributeMaxDynamicSharedMemorySize, LDS_SZ);

  k0b_cb<<<dim3(1024), dim3(64), 0, stream>>>(cb, cbb, hn);
  k1_fused<<<dim3(1024), dim3(256), LDS_SZ, stream>>>(z, cb, cbb, hn, out, pz2, ps);
  k3_loss<<<dim3(1), dim3(256), 0, stream>>>(pz2, ps, out + 16777216);
}